// Round 12
// baseline (226.747 us; speedup 1.0000x reference)
//
#include <hip/hip_runtime.h>
#include <hip/hip_fp16.h>
#include <cmath>

#define BB 8
#define TT 4
#define HH 16
#define DDIM 128
#define RRDIM 64
#define CCDIM 64
#define RANKC 512
#define DMODEL 2048
#define S0C 4096
#define NQ 64      // H*T queries per batch
#define HD 2048    // H*D
#define NACT 3584
#define NSC 65     // 64 cache chunks of 64 + 1 new-token chunk
#define NG 17      // 16 groups of 4 chunks + 1 new-token group
#define SPAD 4160
#define SCALE_ATT 0.08838834764831845f  // 1/sqrt(128)

typedef __attribute__((ext_vector_type(8))) short bf16x8;
typedef __attribute__((ext_vector_type(4))) float f32x4;
typedef unsigned short ushortT;

#define AIDX(row, kk) ((row)*132 + (((row)>>2)<<2) + (kk))

static __device__ __forceinline__ unsigned short f2bf(float x) {
  unsigned u = __float_as_uint(x);
  u += 0x7FFFu + ((u >> 16) & 1u);
  return (unsigned short)(u >> 16);
}
static __device__ __forceinline__ unsigned pk2(float a, float b) {
  return (unsigned)f2bf(a) | ((unsigned)f2bf(b) << 16);
}

// ---------------- L1: front = proj4 (atomic k-split accumulate into act) + cckv transpose + zero/rctab
// blocks [0,448): proj4; [448,2496): transpose (1 slab each); [2496,2504): zero ch64 (+rctab on 2496)
__global__ __launch_bounds__(256) void k_front(const float* __restrict__ A,
                                               const float* __restrict__ w0,
                                               const float* __restrict__ w1,
                                               const float* __restrict__ w2,
                                               const float* __restrict__ w3,
                                               const float* __restrict__ cckv,
                                               float* __restrict__ act,
                                               ushortT* __restrict__ ckvB,
                                               ushortT* __restrict__ ckvT,
                                               float* __restrict__ rctab) {
  __shared__ float shf[4352];
  const int tid = threadIdx.x;
  const int bx = blockIdx.x;
  if (bx < 448) {
    const int cb = bx % 28;
    const int k0 = (bx / 28) * 128;
    const float* W; int N, lc0, off;
    if (cb < 8)       { W = w0; N = 1024; lc0 = cb * 128;        off = 0; }
    else if (cb < 16) { W = w1; N = 1024; lc0 = (cb - 8) * 128;  off = 1024; }
    else if (cb < 20) { W = w2; N = 512;  lc0 = (cb - 16) * 128; off = 2048; }
    else              { W = w3; N = 1024; lc0 = (cb - 20) * 128; off = 2560; }
    {
      const int row = tid >> 3;
      const int kseg = (tid & 7) * 16;
      const float4* s4 = reinterpret_cast<const float4*>(A + (size_t)row * DMODEL + k0 + kseg);
      float4 v0 = s4[0], v1 = s4[1], v2 = s4[2], v3 = s4[3];
      *reinterpret_cast<float4*>(&shf[AIDX(row, kseg)])      = v0;
      *reinterpret_cast<float4*>(&shf[AIDX(row, kseg + 4)])  = v1;
      *reinterpret_cast<float4*>(&shf[AIDX(row, kseg + 8)])  = v2;
      *reinterpret_cast<float4*>(&shf[AIDX(row, kseg + 12)]) = v3;
    }
    __syncthreads();
    const int cg = tid & 31;
    const int rg = tid >> 5;
    float acc[4][4];
    #pragma unroll
    for (int r = 0; r < 4; ++r)
      #pragma unroll
      for (int c = 0; c < 4; ++c) acc[r][c] = 0.f;
    #pragma unroll 4
    for (int kk = 0; kk < 128; ++kk) {
      const float4 w4 = *reinterpret_cast<const float4*>(W + (size_t)(k0 + kk) * N + lc0 + cg * 4);
      const float wv[4] = {w4.x, w4.y, w4.z, w4.w};
      #pragma unroll
      for (int r = 0; r < 4; ++r) {
        const float av = shf[AIDX(rg * 4 + r, kk)];
        #pragma unroll
        for (int c = 0; c < 4; ++c) acc[r][c] = fmaf(av, wv[c], acc[r][c]);
      }
    }
    #pragma unroll
    for (int r = 0; r < 4; ++r)
      #pragma unroll
      for (int c = 0; c < 4; ++c)
        unsafeAtomicAdd(&act[(size_t)(rg * 4 + r) * NACT + off + lc0 + cg * 4 + c], acc[r][c]);
  } else if (bx < 2496) {
    ushortT* tlds = reinterpret_cast<ushortT*>(shf);   // [64 s][136]
    const int idx = bx - 448;
    const int b = idx >> 8, c = (idx >> 2) & 63, slab = idx & 3;
    const int r0 = slab * 128;
    const float* src = cckv + ((size_t)b * S0C + c * 64) * RANKC;
    ushortT* dstB = ckvB + ((size_t)(b * NSC + c) * 64) * RANKC;
    ushortT* dstT = ckvT + ((size_t)(b * NSC + c) * RANKC) * 64;
    const int s = tid >> 2, rq = tid & 3;
    const int rloc = tid >> 1, shalf = (tid & 1) * 32;
    unsigned pk_arr[16];
    #pragma unroll
    for (int i = 0; i < 8; ++i) {
      const float4 v = *reinterpret_cast<const float4*>(src + (size_t)s * RANKC + r0 + rq * 32 + i * 4);
      pk_arr[2 * i]     = pk2(v.x, v.y);
      pk_arr[2 * i + 1] = pk2(v.z, v.w);
      *reinterpret_cast<uint2*>(&tlds[s * 136 + rq * 32 + i * 4]) =
          make_uint2(pk_arr[2 * i], pk_arr[2 * i + 1]);
    }
    { // coalesced row-major bf16 write: 64B contiguous per thread
      uint4* db = reinterpret_cast<uint4*>(dstB + (size_t)s * RANKC + r0 + rq * 32);
      db[0] = make_uint4(pk_arr[0], pk_arr[1], pk_arr[2], pk_arr[3]);
      db[1] = make_uint4(pk_arr[4], pk_arr[5], pk_arr[6], pk_arr[7]);
      db[2] = make_uint4(pk_arr[8], pk_arr[9], pk_arr[10], pk_arr[11]);
      db[3] = make_uint4(pk_arr[12], pk_arr[13], pk_arr[14], pk_arr[15]);
    }
    __syncthreads();
    unsigned pkv[16];
    #pragma unroll
    for (int k = 0; k < 16; ++k) {
      const unsigned t0 = tlds[(shalf + 2 * k)     * 136 + rloc];
      const unsigned t1 = tlds[(shalf + 2 * k + 1) * 136 + rloc];
      pkv[k] = t0 | (t1 << 16);
    }
    uint4* d = reinterpret_cast<uint4*>(dstT + ((size_t)(r0 + rloc)) * 64 + shalf);
    d[0] = make_uint4(pkv[0], pkv[1], pkv[2], pkv[3]);
    d[1] = make_uint4(pkv[4], pkv[5], pkv[6], pkv[7]);
    d[2] = make_uint4(pkv[8], pkv[9], pkv[10], pkv[11]);
    d[3] = make_uint4(pkv[12], pkv[13], pkv[14], pkv[15]);
  } else {
    const int b = bx - 2496;
    const uint4 z = make_uint4(0, 0, 0, 0);
    uint4* p = reinterpret_cast<uint4*>(ckvT + ((size_t)(b * NSC + 64) * RANKC) * 64);
    for (int i = tid; i < 4096; i += 256) p[i] = z;
    uint4* q = reinterpret_cast<uint4*>(ckvB + (((size_t)(b * NSC + 64) * 64) + 4) * RANKC);
    for (int i = tid; i < 3840; i += 256) q[i] = z;
    if (bx == 2496 && tid < 128) {   // rope cos/sin table (double-precision, once)
      const int t = tid >> 5, j = tid & 31;
      const double fr = (double)(S0C + t) * pow(10000.0, -(double)j / 32.0);
      rctab[t * 32 + j]       = (float)cos(fr);
      rctab[128 + t * 32 + j] = (float)sin(fr);
    }
  }
}

// ---------------- L2: mid = rope-scores (direct act reads, 256 s/blk) + qlat + kvd
// blocks [0,2304): rscore; [2304,2368): qlat; [2368,2432): kvd
__global__ __launch_bounds__(256) void k_mid(const float* __restrict__ act,
                                             const float* __restrict__ cache_kr,
                                             const float* __restrict__ wup,
                                             const float* __restrict__ rctab,
                                             ushortT* __restrict__ qlat,
                                             ushortT* __restrict__ ckvB,
                                             ushortT* __restrict__ ckvT,
                                             __half* __restrict__ rs) {
  __shared__ float smid[2176];
  const int tid = threadIdx.x;
  const int bx = blockIdx.x;
  if (bx < 2304) {
    const int bh = bx / 18, sy = bx % 18;
    const int b = bh >> 4, h = bh & 15;
    float* raw_q = smid;          // [4][64]
    float* raw_k = smid + 256;
    float* qr_l  = smid + 512;    // pre-scaled
    float* kr_l  = smid + 768;
    if (tid < 256) {
      const int t = tid >> 6, j = tid & 63;
      const size_t rowoff = (size_t)(b * TT + t) * NACT;
      raw_q[t * 64 + j] = act[rowoff + 1024 + h * 64 + j];
      raw_k[t * 64 + j] = act[rowoff + 2560 + h * 64 + j];
    }
    __syncthreads();
    {
      const int t = tid >> 6, j = tid & 63;
      const int j2 = j & 31;
      const float cs = rctab[t * 32 + j2];
      const float sn = rctab[128 + t * 32 + j2];
      const float qa = raw_q[t * 64 + j], qp = raw_q[t * 64 + (j ^ 32)];
      const float ka = raw_k[t * 64 + j], kp = raw_k[t * 64 + (j ^ 32)];
      float qv, kv;
      if (j < 32) { qv = qa * cs - qp * sn; kv = ka * cs - kp * sn; }
      else        { qv = qp * sn + qa * cs; kv = kp * sn + ka * cs; }
      qr_l[t * 64 + j] = qv * SCALE_ATT;
      kr_l[t * 64 + j] = kv;
    }
    __syncthreads();
    const int ql = tid & 3;
    float4 qf[4][4];
    #pragma unroll
    for (int t = 0; t < 4; ++t)
      #pragma unroll
      for (int u = 0; u < 4; ++u)
        qf[t][u] = *reinterpret_cast<const float4*>(&qr_l[t * 64 + ql * 16 + u * 4]);
    const int s0 = sy * 256;
    #pragma unroll 2
    for (int pass = 0; pass < 4; ++pass) {
      const int s = s0 + pass * 64 + (tid >> 2);
      if (s < 4100) {
        float p[4] = {0.f, 0.f, 0.f, 0.f};
        const float* krow = (s < S0C)
            ? cache_kr + (((size_t)b * S0C + s) * HH + h) * RRDIM
            : &kr_l[(s - S0C) * 64];
        #pragma unroll
        for (int u = 0; u < 4; ++u) {
          const float4 kv = *reinterpret_cast<const float4*>(krow + ql * 16 + u * 4);
          #pragma unroll
          for (int t = 0; t < 4; ++t)
            p[t] += kv.x * qf[t][u].x + kv.y * qf[t][u].y
                  + kv.z * qf[t][u].z + kv.w * qf[t][u].w;
        }
        #pragma unroll
        for (int t = 0; t < 4; ++t) {
          p[t] += __shfl_xor(p[t], 1, 4);
          p[t] += __shfl_xor(p[t], 2, 4);
        }
        rs[((size_t)bh * 4 + ql) * SPAD + s] = __float2half(p[ql]);
      }
    }
  } else if (bx < 2368) {
    const int lx = bx - 2304;
    const int h = lx & 15;
    const int r0 = (lx >> 4) * 128;
    float* a_s = smid;          // 32*68 = 2176
    {
      const int bt = tid >> 3;
      const int c8 = (tid & 7) * 8;
      const float4* pp = reinterpret_cast<const float4*>(act + (size_t)bt * NACT + h * CCDIM + c8);
      const float4 x0 = pp[0], x1 = pp[1];
      a_s[bt * 68 + c8 + 0] = x0.x; a_s[bt * 68 + c8 + 1] = x0.y;
      a_s[bt * 68 + c8 + 2] = x0.z; a_s[bt * 68 + c8 + 3] = x0.w;
      a_s[bt * 68 + c8 + 4] = x1.x; a_s[bt * 68 + c8 + 5] = x1.y;
      a_s[bt * 68 + c8 + 6] = x1.z; a_s[bt * 68 + c8 + 7] = x1.w;
    }
    __syncthreads();
    const int r = tid & 127;
    const int bth = tid >> 7;
    const float* wrow = wup + (size_t)(r0 + r) * HD + h * DDIM;
    float4 wreg[16];
    #pragma unroll
    for (int u = 0; u < 16; ++u)
      wreg[u] = *reinterpret_cast<const float4*>(wrow + u * 4);
    float acc[16];
    #pragma unroll
    for (int i = 0; i < 16; ++i) acc[i] = 0.f;
    #pragma unroll
    for (int u = 0; u < 16; ++u) {
      #pragma unroll
      for (int i = 0; i < 16; ++i) {
        const float4 av = *reinterpret_cast<const float4*>(&a_s[(bth * 16 + i) * 68 + u * 4]);
        acc[i] = fmaf(av.x, wreg[u].x, acc[i]);
        acc[i] = fmaf(av.y, wreg[u].y, acc[i]);
        acc[i] = fmaf(av.z, wreg[u].z, acc[i]);
        acc[i] = fmaf(av.w, wreg[u].w, acc[i]);
      }
    }
    #pragma unroll
    for (int i = 0; i < 16; ++i) {
      const int bt = bth * 16 + i;
      const int b = bt >> 2, t = bt & 3;
      qlat[((size_t)(b * NQ) + h * TT + t) * RANKC + r0 + r] = f2bf(acc[i]);
    }
  } else {
    const int g = (bx - 2368) * 256 + tid;   // 0..16383
    const int r = g & 511;
    const int bt = g >> 9;
    const int b = bt >> 2, t = bt & 3;
    const float s = act[(size_t)bt * NACT + 2048 + r];
    const ushortT bv = f2bf(s);
    ckvB[(((size_t)(b * NSC + 64) * 64) + t) * RANKC + r] = bv;
    ckvT[(((size_t)(b * NSC + 64) * RANKC) + r) * 64 + t] = bv;
  }
}

// ---------------- L3: k_score — direct bf16 ckvB reads, Q in registers, MFMA
// grid (8 b, 65 chunks), 256 thr = 4 waves (wave w = q-strip [16w,16w+16))
__global__ __launch_bounds__(256) void k_score(
    const ushortT* __restrict__ ckvB, const ushortT* __restrict__ qlat,
    const __half* __restrict__ rs, float* __restrict__ ml,
    ushortT* __restrict__ Pg) {
  __shared__ ushortT PL[64 * 72];
  const int tid = threadIdx.x;
  const int wv = tid >> 6;
  const int lane = tid & 63;
  const int lm = lane & 15, lg = lane >> 4;
  const int b = blockIdx.x, chunk = blockIdx.y;
  const int qbase = wv * 16;
  const int scnt = (chunk < 64) ? 64 : TT;
  const ushortT* bsrc = ckvB + ((size_t)(b * NSC + chunk) * 64) * RANKC;

  const ushortT* qrow = qlat + ((size_t)b * NQ + qbase + lm) * RANKC + lg * 8;
  bf16x8 qa[16];
  #pragma unroll
  for (int ks = 0; ks < 16; ++ks)
    qa[ks] = *reinterpret_cast<const bf16x8*>(qrow + ks * 32);

  f32x4 acc[4];
  #pragma unroll
  for (int st = 0; st < 4; ++st) acc[st] = (f32x4){0.f, 0.f, 0.f, 0.f};
  #pragma unroll
  for (int ks = 0; ks < 16; ++ks) {
    #pragma unroll
    for (int st = 0; st < 4; ++st) {
      const bf16x8 bf = *reinterpret_cast<const bf16x8*>(
          bsrc + (size_t)(st * 16 + lm) * RANKC + ks * 32 + lg * 8);
      acc[st] = __builtin_amdgcn_mfma_f32_16x16x32_bf16(qa[ks], bf, acc[st], 0, 0, 0);
    }
  }

  #pragma unroll
  for (int reg = 0; reg < 4; ++reg) {
    const int qi = qbase + lg * 4 + reg;
    const __half* rp = rs + (((size_t)(b * HH) + (qi >> 2)) * TT + (qi & 3)) * SPAD + chunk * 64;
    float vvv[4];
    float mx = -1e30f;
    #pragma unroll
    for (int st = 0; st < 4; ++st) {
      const int sl = st * 16 + lm;
      const float val = (sl < scnt)
          ? fmaf(acc[st][reg], SCALE_ATT, __half2float(rp[sl]))
          : -1e30f;
      vvv[st] = val;
      mx = fmaxf(mx, val);
    }
    #pragma unroll
    for (int off = 1; off < 16; off <<= 1) mx = fmaxf(mx, __shfl_xor(mx, off, 16));
    float sum = 0.f;
    #pragma unroll
    for (int st = 0; st < 4; ++st) {
      const float p = __expf(vvv[st] - mx);
      vvv[st] = p;
      sum += p;
    }
    #pragma unroll
    for (int off = 1; off < 16; off <<= 1) sum += __shfl_xor(sum, off, 16);
    #pragma unroll
    for (int st = 0; st < 4; ++st)
      PL[(qbase + lg * 4 + reg) * 72 + st * 16 + lm] = f2bf(vvv[st]);
    if (lm == 0) {
      const size_t mb = (((size_t)b * NSC + chunk) * NQ + qi) * 2;
      ml[mb] = mx; ml[mb + 1] = sum;
    }
  }
  __syncthreads();
  {
    const int row = tid >> 2, seg = (tid & 3) * 16;
    const uint4* sp = reinterpret_cast<const uint4*>(&PL[row * 72 + seg]);
    uint4* dp = reinterpret_cast<uint4*>(
        Pg + ((size_t)(b * NSC + chunk) * NQ + row) * 64 + seg);
    dp[0] = sp[0]; dp[1] = sp[1];
  }
}

// ---------------- L4: k_pv — zero-LDS zero-barrier group-accumulated PV
// grid (8 b, 17 g, 8 rg of 64 r), 256 thr = 4 waves
__global__ __launch_bounds__(256) void k_pv(
    const ushortT* __restrict__ ckvT, const ushortT* __restrict__ Pg,
    const float* __restrict__ ml, float* __restrict__ olat,
    float* __restrict__ mlg) {
  const int tid = threadIdx.x;
  const int wv = tid >> 6;
  const int lane = tid & 63;
  const int lm = lane & 15, lg = lane >> 4;
  const int b = blockIdx.x, g = blockIdx.y, rg = blockIdx.z;
  const int qbase = wv * 16;
  const int nc = (g < 16) ? 4 : 1;
  const int c0 = (g < 16) ? g * 4 : 64;

  float m_cl = -1e30f, l_cl = 0.f;
  if (lg < nc) {
    const size_t mb = (((size_t)b * NSC + c0 + lg) * NQ + qbase + lm) * 2;
    m_cl = ml[mb]; l_cl = ml[mb + 1];
  }
  float mg = fmaxf(m_cl, __shfl_xor(m_cl, 16));
  mg = fmaxf(mg, __shfl_xor(mg, 32));
  const float wgt = (lg < nc) ? __expf(m_cl - mg) : 0.f;
  float la = l_cl * wgt;
  la += __shfl_xor(la, 16);
  la += __shfl_xor(la, 32);
  if (rg == 0 && lg == 0) {
    const size_t gb = (((size_t)b * NG + g) * NQ + qbase + lm) * 2;
    mlg[gb] = mg; mlg[gb + 1] = la;
  }
  float wf[4][4];
  #pragma unroll
  for (int c = 0; c < 4; ++c)
    #pragma unroll
    for (int reg = 0; reg < 4; ++reg)
      wf[c][reg] = __shfl(wgt, c * 16 + lg * 4 + reg);

  f32x4 OACC[4];
  #pragma unroll
  for (int nt = 0; nt < 4; ++nt) OACC[nt] = (f32x4){0.f, 0.f, 0.f, 0.f};

  for (int c = 0; c < nc; ++c) {
    const ushortT* pb = Pg + ((size_t)(b * NSC + c0 + c) * NQ + qbase + lm) * 64 + lg * 8;
    const bf16x8 pa0 = *reinterpret_cast<const bf16x8*>(pb);
    const bf16x8 pa1 = *reinterpret_cast<const bf16x8*>(pb + 32);
    const ushortT* vb = ckvT + (((size_t)(b * NSC + c0 + c) * RANKC) + rg * 64 + lm) * 64 + lg * 8;
    f32x4 a2[4];
    #pragma unroll
    for (int nt = 0; nt < 4; ++nt) a2[nt] = (f32x4){0.f, 0.f, 0.f, 0.f};
    #pragma unroll
    for (int nt = 0; nt < 4; ++nt) {
      const bf16x8 b0 = *reinterpret_cast<const bf16x8*>(vb + (size_t)nt * 16 * 64);
      const bf16x8 b1 = *reinterpret_cast<const bf16x8*>(vb + (size_t)nt * 16 * 64 + 32);
      a2[nt] = __builtin_amdgcn_mfma_f32_16x16x32_bf16(pa0, b0, a2[nt], 0, 0, 0);
      a2[nt] = __builtin_amdgcn_mfma_f32_16x16x32_bf16(pa1, b1, a2[nt], 0, 0, 0);
    }
    const f32x4 wv4 = {wf[c][0], wf[c][1], wf[c][2], wf[c][3]};
    #pragma unroll
    for (int nt = 0; nt < 4; ++nt) OACC[nt] += wv4 * a2[nt];
  }

  const size_t obase = ((size_t)(b * NG + g) * NQ) * RANKC;
  #pragma unroll
  for (int nt = 0; nt < 4; ++nt)
    #pragma unroll
    for (int reg = 0; reg < 4; ++reg)
      olat[obase + (size_t)(qbase + lg * 4 + reg) * RANKC + rg * 64 + nt * 16 + lm] = OACC[nt][reg];
}

// ---------------- L5: fused combine + out_head epilogue, split by r-quarter (partial ohead atomics)
// grid (16 h, 8 b, 4 rq), 256 threads
__global__ __launch_bounds__(256) void k_combF(const float* __restrict__ mlg,
                                               const float* __restrict__ olat,
                                               const float* __restrict__ wup,
                                               float* __restrict__ ohead) {
  __shared__ float wrow[4][20];
  __shared__ float red[2][4][32][4];
  __shared__ float att_l[4][128];
  const int h = blockIdx.x, b = blockIdx.y, rq = blockIdx.z;
  const int tid = threadIdx.x;
  // stats: wave i = t
  const int i = tid >> 6;
  const int rl = tid & 63;
  const int qi = h * TT + i;
  float m1 = -1e30f, l1 = 0.f;
  if (rl < NG) {
    const size_t base = (((size_t)b * NG + rl) * NQ + qi) * 2;
    m1 = mlg[base]; l1 = mlg[base + 1];
  }
  float M = m1;
  #pragma unroll
  for (int off = 1; off < 64; off <<= 1) M = fmaxf(M, __shfl_xor(M, off));
  float L = (rl < NG) ? l1 * __expf(m1 - M) : 0.f;
  #pragma unroll
  for (int off = 1; off < 64; off <<= 1) L += __shfl_xor(L, off);
  const float invL = 1.0f / L;
  if (rl < NG) wrow[i][rl] = __expf(m1 - M) * invL;
  __syncthreads();
  // phase 1: att for r-range [rq*128, +128), c-loop split across halves
  {
    const int ch = tid >> 7;              // 0: c 0..8, 1: c 9..16
    const int t = (tid >> 5) & 3;
    const int p32 = tid & 31;
    const int qit = h * TT + t;
    const int cbeg = ch ? 9 : 0, cend = ch ? NG : 9;
    float o0 = 0.f, o1 = 0.f, o2 = 0.f, o3 = 0.f;
    for (int c = cbeg; c < cend; ++c) {
      const float w = wrow[t][c];
      const float4 v = *reinterpret_cast<const float4*>(
          olat + (((size_t)b * NG + c) * NQ + qit) * RANKC + rq * 128 + p32 * 4);
      o0 = fmaf(v.x, w, o0); o1 = fmaf(v.y, w, o1);
      o2 = fmaf(v.z, w, o2); o3 = fmaf(v.w, w, o3);
    }
    *reinterpret_cast<float4*>(&red[ch][t][p32][0]) = make_float4(o0, o1, o2, o3);
  }
  __syncthreads();
  if (tid < 128) {
    const int t = tid >> 5, p32 = tid & 31;
    const float4 v0 = *reinterpret_cast<const float4*>(&red[0][t][p32][0]);
    const float4 v1 = *reinterpret_cast<const float4*>(&red[1][t][p32][0]);
    *reinterpret_cast<float4*>(&att_l[t][p32 * 4]) =
        make_float4(v0.x + v1.x, v0.y + v1.y, v0.z + v1.z, v0.w + v1.w);
  }
  __syncthreads();
  // phase 2: partial out_head for this r-quarter; r-walk split across halves
  {
    const int rhalf = tid >> 7;
    const int t = (tid >> 5) & 3;
    const int c4 = tid & 31;
    const float* wb = wup + (size_t)(rq * 128 + rhalf * 64) * HD + h * DDIM + c4 * 4;
    float a0 = 0.f, a1 = 0.f, a2 = 0.f, a3 = 0.f;
    #pragma unroll 4
    for (int rr = 0; rr < 64; ++rr) {
      const float4 w4 = *reinterpret_cast<const float4*>(wb + (size_t)rr * HD);
      const float a = att_l[t][rhalf * 64 + rr];
      a0 = fmaf(a, w4.x, a0); a1 = fmaf(a, w4.y, a1);
      a2 = fmaf(a, w4.z, a2); a3 = fmaf(a, w4.w, a3);
    }
    float* dst = &ohead[(size_t)(b * TT + t) * HD + h * DDIM + c4 * 4];
    unsafeAtomicAdd(dst + 0, a0);
    unsafeAtomicAdd(dst + 1, a1);
    unsafeAtomicAdd(dst + 2, a2);
    unsafeAtomicAdd(dst + 3, a3);
  }
}

// ---------------- L6: k_projA — skinny GEMM, k-splits accumulated into out via fp32 atomics
__global__ __launch_bounds__(256) void k_projA(const float* __restrict__ A,
                                               const float* __restrict__ W,
                                               float* __restrict__ out) {
  __shared__ float a_lds[4352];
  const int tid = threadIdx.x;
  const int c0 = blockIdx.x * 128;
  const int k0 = blockIdx.y * 128;
  {
    const int row = tid >> 3;
    const int kseg = (tid & 7) * 16;
    const float4* s4 = reinterpret_cast<const float4*>(A + (size_t)row * DMODEL + k0 + kseg);
    float4 v0 = s4[0], v1 = s4[1], v2 = s4[2], v3 = s4[3];
    *reinterpret_cast<float4*>(&a_lds[AIDX(row, kseg)])      = v0;
    *reinterpret_cast<float4*>(&a_lds[AIDX(row, kseg + 4)])  = v1;
    *reinterpret_cast<float4*>(&a_lds[AIDX(row, kseg + 8)])  = v2;
    *reinterpret_cast<float4*>(&a_lds[AIDX(row, kseg + 12)]) = v3;
  }
  __syncthreads();
  const int cg = tid & 31;
  const int rg = tid >> 5;
  float acc[4][4];
  #pragma unroll
  for (int r = 0; r < 4; ++r)
    #pragma unroll
    for (int c = 0; c < 4; ++c) acc[r][c] = 0.f;
  #pragma unroll 4
  for (int kk = 0; kk < 128; ++kk) {
    const float4 w4 = *reinterpret_cast<const float4*>(W + (size_t)(k0 + kk) * HD + c0 + cg * 4);
    const float wv[4] = {w4.x, w4.y, w4.z, w4.w};
    #pragma unroll
    for (int r = 0; r < 4; ++r) {
      const float av = a_lds[AIDX(rg * 4 + r, kk)];
      #pragma unroll
      for (int c = 0; c < 4; ++c) acc[r][c] = fmaf(av, wv[c], acc[r][c]);
    }
  }
  #pragma unroll
  for (int r = 0; r < 4; ++r)
    #pragma unroll
    for (int c = 0; c < 4; ++c)
      unsafeAtomicAdd(&out[(size_t)(rg * 4 + r) * HD + c0 + cg * 4 + c], acc[r][c]);
}

extern "C" void kernel_launch(void* const* d_in, const int* in_sizes, int n_in,
                              void* d_out, int out_size, void* d_ws, size_t ws_size,
                              hipStream_t stream) {
  const float* x     = (const float*)d_in[0];
  const float* cckv  = (const float*)d_in[1];
  const float* ckr   = (const float*)d_in[2];
  const float* w_q   = (const float*)d_in[3];
  const float* w_qr  = (const float*)d_in[4];
  const float* w_kvd = (const float*)d_in[5];
  const float* w_kvu = (const float*)d_in[6];
  const float* w_kr  = (const float*)d_in[7];
  const float* w_out = (const float*)d_in[8];
  float* out = (float*)d_out;
  float* ws = (float*)d_ws;

  size_t off = 0;
  float* act      = ws + off; off += 32ull * NACT;                  // 114688 (atomic-accumulated)
  ushortT* qlat   = (ushortT*)(ws + off); off += 131072;            // 8*64*512 bf16
  float* mlb      = ws + off; off += (size_t)BB * NSC * NQ * 2;     // 66560
  float* mlgb     = ws + off; off += (size_t)BB * NG * NQ * 2;      // 17408
  float* ohead    = ws + off; off += 65536;                         // atomic-accumulated
  float* rctab    = ws + off; off += 256;
  __half* rsb     = (__half*)(ws + off); off += 1064960;            // 512*4160 fp16
  ushortT* ckvB   = (ushortT*)(ws + off); off += 8519680;           // 8*65*64*512 bf16
  ushortT* ckvT   = (ushortT*)(ws + off); off += 8519680;
  ushortT* Pgb    = (ushortT*)(ws + off); off += 1064960;           // 520*64*64 bf16
  float* olat     = ws + off;                                       // 8*17*64*512 fp32

  // zero the atomic-accumulated buffers (graph-capturable async memsets)
  hipMemsetAsync(act, 0, 32ull * NACT * sizeof(float), stream);
  hipMemsetAsync(ohead, 0, 65536 * sizeof(float), stream);
  hipMemsetAsync(out, 0, (size_t)out_size * sizeof(float), stream);

  k_front<<<dim3(2504), 256, 0, stream>>>(x, w_q, w_qr, w_kvd, w_kr, cckv, act, ckvB, ckvT, rctab);
  k_mid<<<dim3(2432), 256, 0, stream>>>(act, ckr, w_kvu, rctab, qlat, ckvB, ckvT, rsb);
  k_score<<<dim3(BB, NSC), 256, 0, stream>>>(ckvB, qlat, rsb, mlb, Pgb);
  k_pv<<<dim3(BB, NG, 8), 256, 0, stream>>>(ckvT, Pgb, mlb, olat, mlgb);
  k_combF<<<dim3(16, 8, 4), 256, 0, stream>>>(mlgb, olat, w_kvu, ohead);
  k_projA<<<dim3(16, 16), 256, 0, stream>>>(ohead, w_out, out);
}

// Round 13
// 194.047 us; speedup vs baseline: 1.1685x; 1.1685x over previous
//
#include <hip/hip_runtime.h>
#include <hip/hip_fp16.h>
#include <cmath>

#define BB 8
#define TT 4
#define HH 16
#define DDIM 128
#define RRDIM 64
#define CCDIM 64
#define RANKC 512
#define DMODEL 2048
#define S0C 4096
#define NQ 64      // H*T queries per batch
#define HD 2048    // H*D
#define NACT 3584
#define NSC 65     // 64 cache chunks of 64 + 1 new-token chunk
#define NG 17      // 16 groups of 4 chunks + 1 new-token group
#define SPAD 4160
#define SCALE_ATT 0.08838834764831845f  // 1/sqrt(128)

typedef __attribute__((ext_vector_type(8))) short bf16x8;
typedef __attribute__((ext_vector_type(4))) float f32x4;
typedef unsigned short ushortT;

#define AIDX(row, kk) ((row)*132 + (((row)>>2)<<2) + (kk))

static __device__ __forceinline__ unsigned short f2bf(float x) {
  unsigned u = __float_as_uint(x);
  u += 0x7FFFu + ((u >> 16) & 1u);
  return (unsigned short)(u >> 16);
}
static __device__ __forceinline__ unsigned pk2(float a, float b) {
  return (unsigned)f2bf(a) | ((unsigned)f2bf(b) << 16);
}

// ---------------- L1: front = proj4 k-split + cckv->bf16 transpose + zero-fills + rope table
// blocks [0,448): proj4 -> part0; [448,960): transpose; [960,968): zero ch64 (+rctab on 960)
__global__ __launch_bounds__(256) void k_front(const float* __restrict__ A,
                                               const float* __restrict__ w0,
                                               const float* __restrict__ w1,
                                               const float* __restrict__ w2,
                                               const float* __restrict__ w3,
                                               const float* __restrict__ cckv,
                                               float* __restrict__ part,
                                               ushortT* __restrict__ ckvB,
                                               ushortT* __restrict__ ckvT,
                                               float* __restrict__ rctab) {
  __shared__ float shf[4352];
  const int tid = threadIdx.x;
  const int bx = blockIdx.x;
  if (bx < 448) {
    const int cb = bx % 28;
    const int k0 = (bx / 28) * 128;
    const float* W; int N, lc0, off;
    if (cb < 8)       { W = w0; N = 1024; lc0 = cb * 128;        off = 0; }
    else if (cb < 16) { W = w1; N = 1024; lc0 = (cb - 8) * 128;  off = 1024; }
    else if (cb < 20) { W = w2; N = 512;  lc0 = (cb - 16) * 128; off = 2048; }
    else              { W = w3; N = 1024; lc0 = (cb - 20) * 128; off = 2560; }
    {
      const int row = tid >> 3;
      const int kseg = (tid & 7) * 16;
      const float4* s4 = reinterpret_cast<const float4*>(A + (size_t)row * DMODEL + k0 + kseg);
      float4 v0 = s4[0], v1 = s4[1], v2 = s4[2], v3 = s4[3];
      *reinterpret_cast<float4*>(&shf[AIDX(row, kseg)])      = v0;
      *reinterpret_cast<float4*>(&shf[AIDX(row, kseg + 4)])  = v1;
      *reinterpret_cast<float4*>(&shf[AIDX(row, kseg + 8)])  = v2;
      *reinterpret_cast<float4*>(&shf[AIDX(row, kseg + 12)]) = v3;
    }
    __syncthreads();
    const int cg = tid & 31;
    const int rg = tid >> 5;
    float acc[4][4];
    #pragma unroll
    for (int r = 0; r < 4; ++r)
      #pragma unroll
      for (int c = 0; c < 4; ++c) acc[r][c] = 0.f;
    #pragma unroll 4
    for (int kk = 0; kk < 128; ++kk) {
      const float4 w4 = *reinterpret_cast<const float4*>(W + (size_t)(k0 + kk) * N + lc0 + cg * 4);
      const float wv[4] = {w4.x, w4.y, w4.z, w4.w};
      #pragma unroll
      for (int r = 0; r < 4; ++r) {
        const float av = shf[AIDX(rg * 4 + r, kk)];
        #pragma unroll
        for (int c = 0; c < 4; ++c) acc[r][c] = fmaf(av, wv[c], acc[r][c]);
      }
    }
    #pragma unroll
    for (int r = 0; r < 4; ++r) {
      float4 o = make_float4(acc[r][0], acc[r][1], acc[r][2], acc[r][3]);
      *reinterpret_cast<float4*>(part + ((size_t)(bx / 28) * 32 + rg * 4 + r) * NACT + off + lc0 + cg * 4) = o;
    }
  } else if (bx < 960) {
    ushortT* tlds = reinterpret_cast<ushortT*>(shf);   // [64 s][136]
    const int idx = bx - 448;
    const int b = idx >> 6, c = idx & 63;
    const float* src = cckv + ((size_t)b * S0C + c * 64) * RANKC;
    ushortT* dstB = ckvB + ((size_t)(b * NSC + c) * 64) * RANKC;
    ushortT* dstT = ckvT + ((size_t)(b * NSC + c) * RANKC) * 64;
    const int s = tid >> 2, rq = tid & 3;
    const int rloc = tid >> 1, shalf = (tid & 1) * 32;
    for (int slab = 0; slab < 4; ++slab) {
      const int r0 = slab * 128;
      unsigned pk_arr[16];
      #pragma unroll
      for (int i = 0; i < 8; ++i) {
        const float4 v = *reinterpret_cast<const float4*>(src + (size_t)s * RANKC + r0 + rq * 32 + i * 4);
        pk_arr[2 * i]     = pk2(v.x, v.y);
        pk_arr[2 * i + 1] = pk2(v.z, v.w);
        *reinterpret_cast<uint2*>(&tlds[s * 136 + rq * 32 + i * 4]) =
            make_uint2(pk_arr[2 * i], pk_arr[2 * i + 1]);
      }
      {
        uint4* db = reinterpret_cast<uint4*>(dstB + (size_t)s * RANKC + r0 + rq * 32);
        db[0] = make_uint4(pk_arr[0], pk_arr[1], pk_arr[2], pk_arr[3]);
        db[1] = make_uint4(pk_arr[4], pk_arr[5], pk_arr[6], pk_arr[7]);
        db[2] = make_uint4(pk_arr[8], pk_arr[9], pk_arr[10], pk_arr[11]);
        db[3] = make_uint4(pk_arr[12], pk_arr[13], pk_arr[14], pk_arr[15]);
      }
      __syncthreads();
      unsigned pkv[16];
      #pragma unroll
      for (int k = 0; k < 16; ++k) {
        const unsigned t0 = tlds[(shalf + 2 * k)     * 136 + rloc];
        const unsigned t1 = tlds[(shalf + 2 * k + 1) * 136 + rloc];
        pkv[k] = t0 | (t1 << 16);
      }
      uint4* d = reinterpret_cast<uint4*>(dstT + ((size_t)(r0 + rloc)) * 64 + shalf);
      d[0] = make_uint4(pkv[0], pkv[1], pkv[2], pkv[3]);
      d[1] = make_uint4(pkv[4], pkv[5], pkv[6], pkv[7]);
      d[2] = make_uint4(pkv[8], pkv[9], pkv[10], pkv[11]);
      d[3] = make_uint4(pkv[12], pkv[13], pkv[14], pkv[15]);
      __syncthreads();
    }
  } else {
    const int b = bx - 960;
    const uint4 z = make_uint4(0, 0, 0, 0);
    uint4* p = reinterpret_cast<uint4*>(ckvT + ((size_t)(b * NSC + 64) * RANKC) * 64);
    for (int i = tid; i < 4096; i += 256) p[i] = z;
    uint4* q = reinterpret_cast<uint4*>(ckvB + (((size_t)(b * NSC + 64) * 64) + 4) * RANKC);
    for (int i = tid; i < 3840; i += 256) q[i] = z;
    if (bx == 960 && tid < 128) {
      const int t = tid >> 5, j = tid & 31;
      const double fr = (double)(S0C + t) * pow(10000.0, -(double)j / 32.0);
      rctab[t * 32 + j]       = (float)cos(fr);
      rctab[128 + t * 32 + j] = (float)sin(fr);
    }
  }
}

// ---------------- L2: mid = rope-scores + qlat + kvd; LDS union = 8.7 KB
// blocks [0,1152): rscore; [1152,1216): qlat; [1216,1280): kvd
__global__ __launch_bounds__(256) void k_mid(const float* __restrict__ part0,
                                             const float* __restrict__ cache_kr,
                                             const float* __restrict__ wup,
                                             const float* __restrict__ rctab,
                                             ushortT* __restrict__ qlat,
                                             ushortT* __restrict__ ckvB,
                                             ushortT* __restrict__ ckvT,
                                             __half* __restrict__ rs) {
  __shared__ float smid[2176];
  const int tid = threadIdx.x;
  const int bx = blockIdx.x;
  if (bx < 1152) {
    const int bh = bx / 9, sy = bx % 9;
    const int b = bh >> 4, h = bh & 15;
    float* raw_q = smid;
    float* raw_k = smid + 256;
    float* qr_l  = smid + 512;
    float* kr_l  = smid + 768;
    {
      const int t = tid >> 6, j = tid & 63;
      const size_t rowoff = (size_t)(b * TT + t) * NACT;
      float sq = 0.f, sk = 0.f;
      #pragma unroll 4
      for (int ks = 0; ks < 16; ++ks) {
        const float* pp = part0 + (size_t)ks * (32 * NACT) + rowoff;
        sq += pp[1024 + h * 64 + j];
        sk += pp[2560 + h * 64 + j];
      }
      raw_q[t * 64 + j] = sq;
      raw_k[t * 64 + j] = sk;
    }
    __syncthreads();
    {
      const int t = tid >> 6, j = tid & 63;
      const int j2 = j & 31;
      const float cs = rctab[t * 32 + j2];
      const float sn = rctab[128 + t * 32 + j2];
      const float qa = raw_q[t * 64 + j], qp = raw_q[t * 64 + (j ^ 32)];
      const float ka = raw_k[t * 64 + j], kp = raw_k[t * 64 + (j ^ 32)];
      float qv, kv;
      if (j < 32) { qv = qa * cs - qp * sn; kv = ka * cs - kp * sn; }
      else        { qv = qp * sn + qa * cs; kv = kp * sn + ka * cs; }
      qr_l[t * 64 + j] = qv * SCALE_ATT;
      kr_l[t * 64 + j] = kv;
    }
    __syncthreads();
    const int ql = tid & 3;
    float4 qf[4][4];
    #pragma unroll
    for (int t = 0; t < 4; ++t)
      #pragma unroll
      for (int u = 0; u < 4; ++u)
        qf[t][u] = *reinterpret_cast<const float4*>(&qr_l[t * 64 + ql * 16 + u * 4]);
    const int s0 = sy * 512;
    #pragma unroll 2
    for (int pass = 0; pass < 8; ++pass) {
      const int s = s0 + pass * 64 + (tid >> 2);
      if (s < 4100) {
        float p[4] = {0.f, 0.f, 0.f, 0.f};
        const float* krow = (s < S0C)
            ? cache_kr + (((size_t)b * S0C + s) * HH + h) * RRDIM
            : &kr_l[(s - S0C) * 64];
        #pragma unroll
        for (int u = 0; u < 4; ++u) {
          const float4 kv = *reinterpret_cast<const float4*>(krow + ql * 16 + u * 4);
          #pragma unroll
          for (int t = 0; t < 4; ++t)
            p[t] += kv.x * qf[t][u].x + kv.y * qf[t][u].y
                  + kv.z * qf[t][u].z + kv.w * qf[t][u].w;
        }
        #pragma unroll
        for (int t = 0; t < 4; ++t) {
          p[t] += __shfl_xor(p[t], 1, 4);
          p[t] += __shfl_xor(p[t], 2, 4);
        }
        rs[((size_t)bh * 4 + ql) * SPAD + s] = __float2half(p[ql]);
      }
    }
  } else if (bx < 1216) {
    const int lx = bx - 1152;
    const int h = lx & 15;
    const int r0 = (lx >> 4) * 128;
    float* a_s = smid;
    {
      const int bt = tid >> 3;
      const int c8 = (tid & 7) * 8;
      float v[8] = {0.f,0.f,0.f,0.f,0.f,0.f,0.f,0.f};
      #pragma unroll 4
      for (int ks = 0; ks < 16; ++ks) {
        const float4* pp = reinterpret_cast<const float4*>(
            part0 + (size_t)ks * (32 * NACT) + (size_t)bt * NACT + h * CCDIM + c8);
        const float4 x0 = pp[0], x1 = pp[1];
        v[0]+=x0.x; v[1]+=x0.y; v[2]+=x0.z; v[3]+=x0.w;
        v[4]+=x1.x; v[5]+=x1.y; v[6]+=x1.z; v[7]+=x1.w;
      }
      #pragma unroll
      for (int u = 0; u < 8; ++u) a_s[bt * 68 + c8 + u] = v[u];
    }
    __syncthreads();
    const int r = tid & 127;
    const int bth = tid >> 7;
    const float* wrow = wup + (size_t)(r0 + r) * HD + h * DDIM;
    float4 wreg[16];
    #pragma unroll
    for (int u = 0; u < 16; ++u)
      wreg[u] = *reinterpret_cast<const float4*>(wrow + u * 4);
    float acc[16];
    #pragma unroll
    for (int i = 0; i < 16; ++i) acc[i] = 0.f;
    #pragma unroll
    for (int u = 0; u < 16; ++u) {
      #pragma unroll
      for (int i = 0; i < 16; ++i) {
        const float4 av = *reinterpret_cast<const float4*>(&a_s[(bth * 16 + i) * 68 + u * 4]);
        acc[i] = fmaf(av.x, wreg[u].x, acc[i]);
        acc[i] = fmaf(av.y, wreg[u].y, acc[i]);
        acc[i] = fmaf(av.z, wreg[u].z, acc[i]);
        acc[i] = fmaf(av.w, wreg[u].w, acc[i]);
      }
    }
    #pragma unroll
    for (int i = 0; i < 16; ++i) {
      const int bt = bth * 16 + i;
      const int b = bt >> 2, t = bt & 3;
      qlat[((size_t)(b * NQ) + h * TT + t) * RANKC + r0 + r] = f2bf(acc[i]);
    }
  } else {
    const int g = (bx - 1216) * 256 + tid;
    const int r = g & 511;
    const int bt = g >> 9;
    const int b = bt >> 2, t = bt & 3;
    float s = 0.f;
    #pragma unroll 4
    for (int ks = 0; ks < 16; ++ks)
      s += part0[(size_t)ks * (32 * NACT) + (size_t)bt * NACT + 2048 + r];
    const ushortT bv = f2bf(s);
    ckvB[(((size_t)(b * NSC + 64) * 64) + t) * RANKC + r] = bv;
    ckvT[(((size_t)(b * NSC + 64) * RANKC) + r) * 64 + t] = bv;
  }
}

// ---------------- L3: k_att — fused score (per-chunk, per wave) + group PV (per r-slab, per wave)
// grid (17 g, 8 b, 2 qh), 256 thr = 4 waves. LDS keeps P~, m, l; no Pg/ml global round-trip.
__global__ __launch_bounds__(256) void k_att(
    const ushortT* __restrict__ ckvB, const ushortT* __restrict__ ckvT,
    const ushortT* __restrict__ qlat, const __half* __restrict__ rs,
    float* __restrict__ olat, float* __restrict__ mlg) {
  __shared__ ushortT PL[4][32 * 72];    // P~ [chunk][q 32][s 64 pad 72]
  __shared__ float mlS[4][2][32];       // [chunk][{m,l}][q]
  __shared__ float wS[4][32];           // group weights [chunk][q]
  const int tid = threadIdx.x;
  const int wv = tid >> 6;
  const int lane = tid & 63;
  const int lm = lane & 15, lg = lane >> 4;
  const int g = blockIdx.x, b = blockIdx.y, qh = blockIdx.z;
  const int qbase = qh * 32;
  const int nc = (g < 16) ? 4 : 1;
  const int c0 = (g < 16) ? g * 4 : 64;

  // ---- phase 1: wave wv scores chunk c0+wv (QK^T + rope + softmax -> PL, mlS)
  if (wv < nc) {
    const int myc = c0 + wv;
    const int scnt = (myc < 64) ? 64 : TT;
    const ushortT* bsrc = ckvB + ((size_t)(b * NSC + myc) * 64) * RANKC;
    const ushortT* qrow = qlat + ((size_t)b * NQ + qbase + lm) * RANKC + lg * 8;
    f32x4 acc[2][4];
    #pragma unroll
    for (int qm = 0; qm < 2; ++qm)
      #pragma unroll
      for (int st = 0; st < 4; ++st) acc[qm][st] = (f32x4){0.f, 0.f, 0.f, 0.f};
    #pragma unroll
    for (int ks = 0; ks < 16; ++ks) {
      const bf16x8 qa0 = *reinterpret_cast<const bf16x8*>(qrow + ks * 32);
      const bf16x8 qa1 = *reinterpret_cast<const bf16x8*>(qrow + 16 * RANKC + ks * 32);
      #pragma unroll
      for (int st = 0; st < 4; ++st) {
        const bf16x8 bf = *reinterpret_cast<const bf16x8*>(
            bsrc + (size_t)(st * 16 + lm) * RANKC + ks * 32 + lg * 8);
        acc[0][st] = __builtin_amdgcn_mfma_f32_16x16x32_bf16(qa0, bf, acc[0][st], 0, 0, 0);
        acc[1][st] = __builtin_amdgcn_mfma_f32_16x16x32_bf16(qa1, bf, acc[1][st], 0, 0, 0);
      }
    }
    #pragma unroll
    for (int qm = 0; qm < 2; ++qm) {
      #pragma unroll
      for (int reg = 0; reg < 4; ++reg) {
        const int ql = qm * 16 + lg * 4 + reg;
        const int qi = qbase + ql;
        const __half* rp = rs + (((size_t)(b * HH) + (qi >> 2)) * TT + (qi & 3)) * SPAD + myc * 64;
        float vvv[4];
        float mx = -1e30f;
        #pragma unroll
        for (int st = 0; st < 4; ++st) {
          const int sl = st * 16 + lm;
          const float val = (sl < scnt)
              ? fmaf(acc[qm][st][reg], SCALE_ATT, __half2float(rp[sl]))
              : -1e30f;
          vvv[st] = val;
          mx = fmaxf(mx, val);
        }
        #pragma unroll
        for (int off = 1; off < 16; off <<= 1) mx = fmaxf(mx, __shfl_xor(mx, off, 16));
        float sum = 0.f;
        #pragma unroll
        for (int st = 0; st < 4; ++st) {
          const float p = __expf(vvv[st] - mx);
          vvv[st] = p;
          sum += p;
        }
        #pragma unroll
        for (int off = 1; off < 16; off <<= 1) sum += __shfl_xor(sum, off, 16);
        #pragma unroll
        for (int st = 0; st < 4; ++st)
          PL[wv][ql * 72 + st * 16 + lm] = f2bf(vvv[st]);
        if (lm == 0) { mlS[wv][0][ql] = mx; mlS[wv][1][ql] = sum; }
      }
    }
  }
  __syncthreads();

  // ---- phase 2: group stats + weights
  if (tid < 32) {
    const int q = tid;
    float mg = -1e30f;
    for (int c = 0; c < nc; ++c) mg = fmaxf(mg, mlS[c][0][q]);
    float la = 0.f;
    for (int c = 0; c < nc; ++c) {
      const float w = __expf(mlS[c][0][q] - mg);
      wS[c][q] = w;
      la = fmaf(mlS[c][1][q], w, la);
    }
    const size_t gb = (((size_t)b * NG + g) * NQ + qbase + q) * 2;
    mlg[gb] = mg; mlg[gb + 1] = la;
  }
  __syncthreads();

  // ---- phase 3: PV, wave wv = r-slab rg (128 r); O[32q][128r] = sum_c w_c * (P~_c . V_c)
  const int rg = wv;
  f32x4 OACC[2][8];
  #pragma unroll
  for (int qm = 0; qm < 2; ++qm)
    #pragma unroll
    for (int rn = 0; rn < 8; ++rn) OACC[qm][rn] = (f32x4){0.f, 0.f, 0.f, 0.f};
  for (int c = 0; c < nc; ++c) {
    const bf16x8 pa00 = *reinterpret_cast<const bf16x8*>(&PL[c][lm * 72 + lg * 8]);
    const bf16x8 pa01 = *reinterpret_cast<const bf16x8*>(&PL[c][lm * 72 + 32 + lg * 8]);
    const bf16x8 pa10 = *reinterpret_cast<const bf16x8*>(&PL[c][(16 + lm) * 72 + lg * 8]);
    const bf16x8 pa11 = *reinterpret_cast<const bf16x8*>(&PL[c][(16 + lm) * 72 + 32 + lg * 8]);
    const f32x4 w0 = {wS[c][lg * 4 + 0], wS[c][lg * 4 + 1], wS[c][lg * 4 + 2], wS[c][lg * 4 + 3]};
    const f32x4 w1 = {wS[c][16 + lg * 4 + 0], wS[c][16 + lg * 4 + 1],
                      wS[c][16 + lg * 4 + 2], wS[c][16 + lg * 4 + 3]};
    const ushortT* vb = ckvT + ((size_t)(b * NSC + c0 + c) * RANKC + rg * 128 + lm) * 64 + lg * 8;
    #pragma unroll
    for (int rn = 0; rn < 8; ++rn) {
      const bf16x8 b0 = *reinterpret_cast<const bf16x8*>(vb + (size_t)rn * 16 * 64);
      const bf16x8 b1 = *reinterpret_cast<const bf16x8*>(vb + (size_t)rn * 16 * 64 + 32);
      f32x4 t0 = (f32x4){0.f, 0.f, 0.f, 0.f}, t1 = (f32x4){0.f, 0.f, 0.f, 0.f};
      t0 = __builtin_amdgcn_mfma_f32_16x16x32_bf16(pa00, b0, t0, 0, 0, 0);
      t0 = __builtin_amdgcn_mfma_f32_16x16x32_bf16(pa01, b1, t0, 0, 0, 0);
      t1 = __builtin_amdgcn_mfma_f32_16x16x32_bf16(pa10, b0, t1, 0, 0, 0);
      t1 = __builtin_amdgcn_mfma_f32_16x16x32_bf16(pa11, b1, t1, 0, 0, 0);
      OACC[0][rn] += w0 * t0;
      OACC[1][rn] += w1 * t1;
    }
  }
  const size_t obase = ((size_t)(b * NG + g) * NQ) * RANKC;
  #pragma unroll
  for (int qm = 0; qm < 2; ++qm)
    #pragma unroll
    for (int rn = 0; rn < 8; ++rn)
      #pragma unroll
      for (int reg = 0; reg < 4; ++reg)
        olat[obase + (size_t)(qbase + qm * 16 + lg * 4 + reg) * RANKC + rg * 128 + rn * 16 + lm]
            = OACC[qm][rn][reg];
}

// ---------------- L4: fused combine + out_head epilogue + out-zero
__global__ __launch_bounds__(512) void k_combF(const float* __restrict__ mlg,
                                               const float* __restrict__ olat,
                                               const float* __restrict__ wup,
                                               float* __restrict__ ohead,
                                               float* __restrict__ out) {
  __shared__ float wrow[4][20];
  __shared__ float att_lds[4][516];
  __shared__ float red[4][4][32][4];
  const int h = blockIdx.x, b = blockIdx.y;
  const int tid = threadIdx.x;
  {
    const int t = tid >> 7, col = tid & 127;
    out[(size_t)(b * TT + t) * HD + h * DDIM + col] = 0.f;
  }
  const int wave = tid >> 6;
  const int i = wave >> 1;
  const int rhalf = wave & 1;
  const int rl = tid & 63;
  const int qi = h * TT + i;
  float m1 = -1e30f, l1 = 0.f;
  if (rl < NG) {
    const size_t base = (((size_t)b * NG + rl) * NQ + qi) * 2;
    m1 = mlg[base]; l1 = mlg[base + 1];
  }
  float M = m1;
  #pragma unroll
  for (int off = 1; off < 64; off <<= 1) M = fmaxf(M, __shfl_xor(M, off));
  float L = (rl < NG) ? l1 * __expf(m1 - M) : 0.f;
  #pragma unroll
  for (int off = 1; off < 64; off <<= 1) L += __shfl_xor(L, off);
  const float invL = 1.0f / L;
  if (rl < NG) wrow[i][rl] = __expf(m1 - M) * invL;
  __syncthreads();
  const int r0 = rhalf * 256 + rl * 4;
  {
    float o0 = 0.f, o1 = 0.f, o2 = 0.f, o3 = 0.f;
    for (int c = 0; c < NG; ++c) {
      const float w = wrow[i][c];
      const float4 v = *reinterpret_cast<const float4*>(
          olat + (((size_t)b * NG + c) * NQ + qi) * RANKC + r0);
      o0 = fmaf(v.x, w, o0); o1 = fmaf(v.y, w, o1);
      o2 = fmaf(v.z, w, o2); o3 = fmaf(v.w, w, o3);
    }
    *reinterpret_cast<float4*>(&att_lds[i][r0]) = make_float4(o0, o1, o2, o3);
  }
  __syncthreads();
  const int t = tid >> 7;
  const int rq = (tid >> 5) & 3;
  const int c4 = tid & 31;
  const float* wb = wup + (size_t)h * DDIM + c4 * 4;
  float a0 = 0.f, a1 = 0.f, a2 = 0.f, a3 = 0.f;
  const int rbeg = rq * 128;
  #pragma unroll 4
  for (int rr = 0; rr < 128; ++rr) {
    const int r = rbeg + rr;
    const float4 w4 = *reinterpret_cast<const float4*>(wb + (size_t)r * HD);
    const float a = att_lds[t][r];
    a0 = fmaf(a, w4.x, a0); a1 = fmaf(a, w4.y, a1);
    a2 = fmaf(a, w4.z, a2); a3 = fmaf(a, w4.w, a3);
  }
  *reinterpret_cast<float4*>(&red[rq][t][c4][0]) = make_float4(a0, a1, a2, a3);
  __syncthreads();
  if (tid < 128) {
    const int t2 = tid >> 5, c42 = tid & 31;
    float4 s = make_float4(0.f, 0.f, 0.f, 0.f);
    #pragma unroll
    for (int q = 0; q < 4; ++q) {
      const float4 v = *reinterpret_cast<const float4*>(&red[q][t2][c42][0]);
      s.x += v.x; s.y += v.y; s.z += v.z; s.w += v.w;
    }
    *reinterpret_cast<float4*>(&ohead[(size_t)(b * TT + t2) * HD + h * DDIM + c42 * 4]) = s;
  }
}

// ---------------- L5: k_projA — skinny GEMM, k-splits accumulated into out via fp32 atomics
__global__ __launch_bounds__(256) void k_projA(const float* __restrict__ A,
                                               const float* __restrict__ W,
                                               float* __restrict__ out) {
  __shared__ float a_lds[4352];
  const int tid = threadIdx.x;
  const int c0 = blockIdx.x * 128;
  const int k0 = blockIdx.y * 128;
  {
    const int row = tid >> 3;
    const int kseg = (tid & 7) * 16;
    const float4* s4 = reinterpret_cast<const float4*>(A + (size_t)row * DMODEL + k0 + kseg);
    float4 v0 = s4[0], v1 = s4[1], v2 = s4[2], v3 = s4[3];
    *reinterpret_cast<float4*>(&a_lds[AIDX(row, kseg)])      = v0;
    *reinterpret_cast<float4*>(&a_lds[AIDX(row, kseg + 4)])  = v1;
    *reinterpret_cast<float4*>(&a_lds[AIDX(row, kseg + 8)])  = v2;
    *reinterpret_cast<float4*>(&a_lds[AIDX(row, kseg + 12)]) = v3;
  }
  __syncthreads();
  const int cg = tid & 31;
  const int rg = tid >> 5;
  float acc[4][4];
  #pragma unroll
  for (int r = 0; r < 4; ++r)
    #pragma unroll
    for (int c = 0; c < 4; ++c) acc[r][c] = 0.f;
  #pragma unroll 4
  for (int kk = 0; kk < 128; ++kk) {
    const float4 w4 = *reinterpret_cast<const float4*>(W + (size_t)(k0 + kk) * HD + c0 + cg * 4);
    const float wv[4] = {w4.x, w4.y, w4.z, w4.w};
    #pragma unroll
    for (int r = 0; r < 4; ++r) {
      const float av = a_lds[AIDX(rg * 4 + r, kk)];
      #pragma unroll
      for (int c = 0; c < 4; ++c) acc[r][c] = fmaf(av, wv[c], acc[r][c]);
    }
  }
  #pragma unroll
  for (int r = 0; r < 4; ++r)
    #pragma unroll
    for (int c = 0; c < 4; ++c)
      unsafeAtomicAdd(&out[(size_t)(rg * 4 + r) * HD + c0 + cg * 4 + c], acc[r][c]);
}

extern "C" void kernel_launch(void* const* d_in, const int* in_sizes, int n_in,
                              void* d_out, int out_size, void* d_ws, size_t ws_size,
                              hipStream_t stream) {
  const float* x     = (const float*)d_in[0];
  const float* cckv  = (const float*)d_in[1];
  const float* ckr   = (const float*)d_in[2];
  const float* w_q   = (const float*)d_in[3];
  const float* w_qr  = (const float*)d_in[4];
  const float* w_kvd = (const float*)d_in[5];
  const float* w_kvu = (const float*)d_in[6];
  const float* w_kr  = (const float*)d_in[7];
  const float* w_out = (const float*)d_in[8];
  float* out = (float*)d_out;
  float* ws = (float*)d_ws;

  size_t off = 0;
  ushortT* qlat   = (ushortT*)(ws + off); off += 131072;            // 8*64*512 bf16 = 512 KB
  float* mlgb     = ws + off; off += (size_t)BB * NG * NQ * 2;      // 17408
  float* ohead    = ws + off; off += 65536;
  float* rctab    = ws + off; off += 256;
  __half* rsb     = (__half*)(ws + off); off += 1064960;            // 512*4160 fp16
  ushortT* ckvB   = (ushortT*)(ws + off); off += 8519680;           // 8*65*64*512 bf16
  ushortT* ckvT   = (ushortT*)(ws + off); off += 8519680;
  // region B (time-shared): part0 -> olat(fp32)
  float* regB  = ws + off;
  float* part0 = regB;                  // 16*32*3584 = 1,835,008 f
  float* olat  = regB;                  // 8*17*64*512 = 4,456,448 f (max)

  k_front<<<dim3(968), 256, 0, stream>>>(x, w_q, w_qr, w_kvd, w_kr, cckv, part0, ckvB, ckvT, rctab);
  k_mid<<<dim3(1280), 256, 0, stream>>>(part0, ckr, w_kvu, rctab, qlat, ckvB, ckvT, rsb);
  k_att<<<dim3(NG, BB, 2), 256, 0, stream>>>(ckvB, ckvT, qlat, rsb, olat, mlgb);
  k_combF<<<dim3(16, 8), 512, 0, stream>>>(mlgb, olat, w_kvu, ohead, out);
  k_projA<<<dim3(16, 16), 256, 0, stream>>>(ohead, w_out, out);
}